// Round 1
// baseline (78.624 us; speedup 1.0000x reference)
//
#include <hip/hip_runtime.h>
#include <hip/hip_bf16.h>
#include <math.h>

// Problem constants (from reference setup_inputs / module constants)
constexpr int N_    = 2;
constexpr int C_TOT = 256;   // C * N_ORI
constexpr int H_    = 128;
constexpr int W_    = 128;
constexpr int OUTS  = 7;     // OUT_SIZE
constexpr int NBIN  = OUTS * OUTS;          // 49
constexpr int SAMP  = 2;     // SAMPLE_NUM
constexpr int NSAMP = NBIN * SAMP * SAMP;   // 196 sample points per roi
constexpr int NORI  = 8;
constexpr int PCH   = C_TOT * NBIN;         // 12544 outputs per roi
constexpr float SCALE = 0.125f;

// ---------------------------------------------------------------------------
// NCHW -> NHWC transpose of features into workspace.
// block (64,4); grid (W/64, C/64, N*H). LDS tile padded to kill bank conflicts.
// ---------------------------------------------------------------------------
__global__ __launch_bounds__(256) void transpose_nchw_nhwc(
    const float* __restrict__ in, float* __restrict__ out) {
  __shared__ float tile[64][65];
  const int nh = blockIdx.z;
  const int n  = nh >> 7;        // H_ = 128
  const int h  = nh & 127;
  const int c0 = blockIdx.y * 64;
  const int w0 = blockIdx.x * 64;
  const int tx = threadIdx.x;    // 0..63
  const int ty = threadIdx.y;    // 0..3

  const float* src = in + (((size_t)n * C_TOT + c0) * H_ + h) * W_ + w0;
#pragma unroll
  for (int i = 0; i < 16; ++i) {
    const int c = i * 4 + ty;
    tile[c][tx] = src[(size_t)c * (H_ * W_) + tx];   // coalesced along w
  }
  __syncthreads();
  float* dst = out + (((size_t)n * H_ + h) * W_ + w0) * C_TOT + c0;
#pragma unroll
  for (int i = 0; i < 16; ++i) {
    const int w = i * 4 + ty;
    dst[(size_t)w * C_TOT + tx] = tile[tx][w];       // coalesced along c
  }
}

// ---------------------------------------------------------------------------
// Main kernel: one block (256 threads) per roi.
//   phase 1: threads 0..195 compute the 196 sample coords -> corner indices +
//            weights (validity & 1/4 averaging folded into weights) in LDS
//   phase 2: thread t = channel c_tot accumulates 49 pooled bins via
//            gathers (coalesced across channels when NHWC), orientation-mixes
//            via __shfl within 8-lane groups, stages results in LDS
//   phase 3: coalesced float4 write of the 12544 outputs for this roi
// ---------------------------------------------------------------------------
template <bool NHWC>
__global__ __launch_bounds__(256) void os2_rroialign(
    const float* __restrict__ ft, const float* __restrict__ rois,
    float* __restrict__ out) {
  __shared__ __align__(16) float outBuf[PCH];   // 49 KiB
  __shared__ int4   sIdx[NSAMP];
  __shared__ float4 sW[NSAMP];

  const int k = blockIdx.x;
  const int t = threadIdx.x;

  const float* roi = rois + (size_t)k * 6;
  const float bf = roi[0];
  const float th = roi[5];
  const int   b  = (int)bf;
  const float cx = roi[1] * SCALE;
  const float cy = roi[2] * SCALE;
  const float rw = fmaxf(roi[3] * SCALE, 1.0f);
  const float rh = fmaxf(roi[4] * SCALE, 1.0f);
  const float binw = rw / (float)OUTS;
  const float binh = rh / (float)OUTS;
  const float cs = cosf(th);
  const float sn = sinf(th);

  if (t < NSAMP) {
    const int bin = t >> 2;
    const int sub = t & 3;          // iy*2 + ix
    const int ph  = bin / 7;
    const int pw  = bin - ph * 7;
    const float fy = (float)ph + ((float)(sub >> 1) + 0.5f) * 0.5f;
    const float fx = (float)pw + ((float)(sub & 1)  + 0.5f) * 0.5f;
    const float yy = -rh * 0.5f + fy * binh;
    const float xx = -rw * 0.5f + fx * binw;
    float x = xx * cs - yy * sn + cx;
    float y = xx * sn + yy * cs + cy;
    const bool valid = (y >= -1.0f) && (y <= (float)H_) &&
                       (x >= -1.0f) && (x <= (float)W_);
    y = fminf(fmaxf(y, 0.0f), (float)(H_ - 1));
    x = fminf(fmaxf(x, 0.0f), (float)(W_ - 1));
    int y0 = (int)floorf(y); if (y0 > H_ - 1) y0 = H_ - 1;
    int x0 = (int)floorf(x); if (x0 > W_ - 1) x0 = W_ - 1;
    const int y1 = min(y0 + 1, H_ - 1);
    const int x1 = min(x0 + 1, W_ - 1);
    const float ly = y - (float)y0, lx = x - (float)x0;
    const float hy = 1.0f - ly,     hx = 1.0f - lx;
    const float m  = valid ? 0.25f : 0.0f;
    sW[t] = make_float4(hy * hx * m, hy * lx * m, ly * hx * m, ly * lx * m);
    if (NHWC) {
      const int pb = b * (H_ * W_);
      sIdx[t] = make_int4((pb + y0 * W_ + x0) * C_TOT,
                          (pb + y0 * W_ + x1) * C_TOT,
                          (pb + y1 * W_ + x0) * C_TOT,
                          (pb + y1 * W_ + x1) * C_TOT);
    } else {
      const int cb = b * C_TOT * H_ * W_;
      sIdx[t] = make_int4(cb + y0 * W_ + x0, cb + y0 * W_ + x1,
                          cb + y1 * W_ + x0, cb + y1 * W_ + x1);
    }
  }

  // orientation interpolation params (same formulas as reference, fp32)
  const float indf = (th * 8.0f) / 6.28318530717958647692f;
  const float i0f  = floorf(indf);
  const float lv   = indf - i0f;
  const float rv   = 1.0f - lv;
  const int ind0 = ((int)i0f) & 7;          // th >= 0 -> i0f >= 0
  const int o    = t & 7;
  const int ir   = (o - ind0) & 7;          // mod 8, two's-complement safe
  const int irp  = (ir + 1) & 7;
  const int grp  = t & 56;                  // 8-lane group base within wave
  const int chanOff = NHWC ? t : t * (H_ * W_);

  __syncthreads();

  for (int bin = 0; bin < NBIN; ++bin) {
    float acc = 0.0f;
#pragma unroll
    for (int s = 0; s < 4; ++s) {
      const int4   id = sIdx[bin * 4 + s];
      const float4 w  = sW[bin * 4 + s];
      acc = fmaf(w.x, ft[id.x + chanOff], acc);
      acc = fmaf(w.y, ft[id.y + chanOff], acc);
      acc = fmaf(w.z, ft[id.z + chanOff], acc);
      acc = fmaf(w.w, ft[id.w + chanOff], acc);
    }
    // orientation mix: need pooled at channels c*8+ir and c*8+irp (same wave)
    const float v1 = __shfl(acc, grp | ir,  64);
    const float v2 = __shfl(acc, grp | irp, 64);
    outBuf[t * NBIN + bin] = rv * v1 + lv * v2;
  }

  __syncthreads();
  const float4* ob4 = (const float4*)outBuf;
  float4* o4 = (float4*)(out + (size_t)k * PCH);
#pragma unroll 4
  for (int j = t; j < PCH / 4; j += 256) o4[j] = ob4[j];
}

// ---------------------------------------------------------------------------
extern "C" void kernel_launch(void* const* d_in, const int* in_sizes, int n_in,
                              void* d_out, int out_size, void* d_ws, size_t ws_size,
                              hipStream_t stream) {
  const float* features = (const float*)d_in[0];
  const float* rois     = (const float*)d_in[1];
  float* out            = (float*)d_out;
  const int K = in_sizes[1] / 6;

  const size_t ftBytes = (size_t)N_ * C_TOT * H_ * W_ * sizeof(float);
  if (ws_size >= ftBytes) {
    float* ftT = (float*)d_ws;
    dim3 tb(64, 4);
    dim3 tg(W_ / 64, C_TOT / 64, N_ * H_);
    transpose_nchw_nhwc<<<tg, tb, 0, stream>>>(features, ftT);
    os2_rroialign<true><<<K, 256, 0, stream>>>(ftT, rois, out);
  } else {
    os2_rroialign<false><<<K, 256, 0, stream>>>(features, rois, out);
  }
}